// Round 8
// baseline (771.429 us; speedup 1.0000x reference)
//
#include <hip/hip_runtime.h>

#define KVOX 12000
#define TPTS 35
#define FIN  7
#define DD   10
#define HH   400
#define WW   352
#define CO   128
#define EPSBN 1e-3f
#define NCELL (DD * HH * WW)              // 1,408,000 cells
#define TOTALF4 ((size_t)NCELL * 32)      // 45,056,000 float4s = 720.9 MB
#define CB    3000                        // fused blocks (4 waves = 4 voxels each)
#define F4PB  15019                       // ceil(TOTALF4 / CB) float4s per block chunk
#define SB    1500                        // scatter kernel blocks

static_assert(CB * 4 == KVOX, "grid covers voxels exactly");
static_assert((size_t)CB * F4PB >= TOTALF4, "fill chunks cover output");

// wave-local LDS fence: cross-lane comm within ONE wave needs only
// lgkmcnt(0) + a compiler reordering barrier — NOT s_barrier (which forces
// vmcnt(0) and would drain our in-flight fill stores).
__device__ __forceinline__ void wave_lds_fence() {
    asm volatile("s_waitcnt lgkmcnt(0)" ::: "memory");
    __builtin_amdgcn_wave_barrier();
}

// ---- fused, barrier-free: zero-fill `out` + compute voxelwise into ws ----
// Per wave: loads (feat+weights) -> full waitcnt fence -> issue entire fill
// chunk (fire-and-forget stores) -> pure DS/VALU compute -> vox stores.
// No s_barrier anywhere, so fill stores stay outstanding across compute.
__global__ __launch_bounds__(256) void fused_fill_compute(
    const float* __restrict__ feat,
    const float* __restrict__ w1, const float* __restrict__ b1,
    const float* __restrict__ g1, const float* __restrict__ be1,
    const float* __restrict__ m1, const float* __restrict__ v1,
    const float* __restrict__ w2, const float* __restrict__ b2,
    const float* __restrict__ g2, const float* __restrict__ be2,
    const float* __restrict__ m2, const float* __restrict__ v2,
    float* __restrict__ vox,          // [KVOX, 128]
    float* __restrict__ out)
{
    const int tid  = threadIdx.x;
    const int wv   = tid >> 6;        // wave in block: 0..3
    const int lane = tid & 63;
    const int k    = blockIdx.x * 4 + wv;

    __shared__ __align__(16) float sxp[4][TPTS][8];    // padded point features
    __shared__ __align__(16) float spwm[4][TPTS][16];  // masked stage-1 pointwise
    __shared__ __align__(16) float sagg[4][16];        // stage-1 aggregate (unmasked)

    // ---------- phase 0: ALL global loads up front ----------
    // stage-2 weights (every lane)
    float w2c[32];
    #pragma unroll
    for (int u = 0; u < 32; ++u) w2c[u] = w2[u * 64 + lane];
    const float b2v    = b2[lane];
    const float scale2 = g2[lane] * rsqrtf(v2[lane] + EPSBN);
    const float shift2 = be2[lane] - m2[lane] * scale2;

    // stage-1 weights (lanes < 16)
    float w1c[8];
    float b1v = 0.f, scale1 = 0.f, shift1 = 0.f;
    if (lane < 16) {
        #pragma unroll
        for (int f = 0; f < FIN; ++f) w1c[f] = w1[f * 16 + lane];
        w1c[FIN] = 0.0f;
        b1v    = b1[lane];
        scale1 = g1[lane] * rsqrtf(v1[lane] + EPSBN);
        shift1 = be1[lane] - m1[lane] * scale1;
    }

    // feat -> LDS (padded rows of 8)
    const float* fk = feat + (size_t)k * (TPTS * FIN);
    for (int i = lane; i < TPTS * FIN; i += 64)
        sxp[wv][i / FIN][i % FIN] = fk[i];
    if (lane < TPTS) sxp[wv][lane][FIN] = 0.0f;

    // mask per point from global (rows are register-resident after load)
    bool pred = false;
    if (lane < TPTS) {
        const float* row = fk + lane * FIN;
        float mx = row[0];
        #pragma unroll
        for (int f = 1; f < FIN; ++f) mx = fmaxf(mx, row[f]);
        pred = (mx != 0.0f);
    }
    const unsigned long long bal = __ballot(pred);   // bit t = mask[t] (wave-uniform)
    const int nvalid = __popcll(bal);

    // everything loaded & staged; nothing after this waits on vmcnt again
    asm volatile("s_waitcnt vmcnt(0) lgkmcnt(0)" ::: "memory");
    __builtin_amdgcn_wave_barrier();

    // ---------- phase 1: issue the block's entire fill chunk ----------
    // 59 dwordx4 stores/lane, fire-and-forget (vmcnt max 63); they drain at
    // HBM rate while phases 2-3 run pure DS/VALU work.
    {
        const float4 z = make_float4(0.f, 0.f, 0.f, 0.f);
        float4* o4 = (float4*)out;
        const size_t base = (size_t)blockIdx.x * F4PB;
        const size_t end  = min(base + F4PB, TOTALF4);
        for (size_t i = base + tid; i < end; i += 256)
            o4[i] = z;
    }

    // ---------- phase 2: stage 1 on lanes u<16 (DS + VALU only) ----------
    if (lane < 16) {
        const int u = lane;
        float agg = -INFINITY;
        float pw[TPTS];
        #pragma unroll
        for (int t = 0; t < TPTS; ++t) {
            const float4 xa = *(const float4*)&sxp[wv][t][0];  // broadcast b128
            const float4 xb = *(const float4*)&sxp[wv][t][4];
            float d = b1v;
            d = fmaf(xa.x, w1c[0], d); d = fmaf(xa.y, w1c[1], d);
            d = fmaf(xa.z, w1c[2], d); d = fmaf(xa.w, w1c[3], d);
            d = fmaf(xb.x, w1c[4], d); d = fmaf(xb.y, w1c[5], d);
            d = fmaf(xb.z, w1c[6], d); d = fmaf(xb.w, w1c[7], d);
            d = fmaxf(d, 0.0f);
            const float p = fmaf(d, scale1, shift1);
            agg = fmaxf(agg, p);
            pw[t] = p;
        }
        sagg[wv][u] = agg;
        #pragma unroll
        for (int t = 0; t < TPTS; ++t) {
            const float mk = ((bal >> t) & 1ULL) ? 1.0f : 0.0f;
            spwm[wv][t][u] = pw[t] * mk;     // banks (t*16+u)%32: conflict-free
        }
    }
    wave_lds_fence();   // wave-local: stage-1 LDS writes -> stage-2 reads

    // ---------- phase 3: stage 2, channel v per lane (DS + VALU only) ----------
    {
        const int v = lane;
        float aggdot = 0.0f;                // sum_u agg[u]*w2c[16+u], t-independent
        {
            const float4* ar = (const float4*)&sagg[wv][0];
            #pragma unroll
            for (int q = 0; q < 4; ++q) {
                const float4 a = ar[q];
                aggdot = fmaf(a.x, w2c[16 + 4 * q + 0], aggdot);
                aggdot = fmaf(a.y, w2c[16 + 4 * q + 1], aggdot);
                aggdot = fmaf(a.z, w2c[16 + 4 * q + 2], aggdot);
                aggdot = fmaf(a.w, w2c[16 + 4 * q + 3], aggdot);
            }
        }

        float aggAll = -INFINITY;
        float voxA   = -INFINITY;
        #pragma unroll 7
        for (int t = 0; t < TPTS; ++t) {
            const float mk = ((bal >> t) & 1ULL) ? 1.0f : 0.0f;
            const float4* xr = (const float4*)&spwm[wv][t][0];
            float d = fmaf(mk, aggdot, b2v);
            #pragma unroll
            for (int q = 0; q < 4; ++q) {
                const float4 xv = xr[q];          // broadcast b128
                d = fmaf(xv.x, w2c[4 * q + 0], d);
                d = fmaf(xv.y, w2c[4 * q + 1], d);
                d = fmaf(xv.z, w2c[4 * q + 2], d);
                d = fmaf(xv.w, w2c[4 * q + 3], d);
            }
            d = fmaxf(d, 0.0f);
            const float p = fmaf(d, scale2, shift2);
            aggAll = fmaxf(aggAll, p);
            voxA   = fmaxf(voxA, p * mk);
        }
        float voxB;
        if (nvalid == 0)          voxB = 0.0f;
        else if (nvalid < TPTS)   voxB = fmaxf(aggAll, 0.0f);
        else                      voxB = aggAll;

        float* vk = vox + (size_t)k * CO;
        vk[v]      = voxA;
        vk[64 + v] = voxB;
    }
}

// ---- tiny scatter: out[cell(k)*128 + ch] += vox[k*128 + ch] (dups accumulate) ----
__global__ __launch_bounds__(256) void scatter_add(
    const float* __restrict__ vox, const int* __restrict__ coord,
    float* __restrict__ out)
{
    const int stride = SB * 256;
    for (int i = blockIdx.x * 256 + threadIdx.x; i < KVOX * CO; i += stride) {
        const int k  = i >> 7;
        const int ch = i & (CO - 1);
        const int4 c = ((const int4*)coord)[k];   // 128 lanes share k -> L1 broadcast
        const int loc = (((c.x * DD + c.y) * HH + c.z) * WW + c.w);
        atomicAdd(out + (size_t)loc * CO + ch, vox[i]);
    }
}

// ---- fallback if ws is too small (R1 path) ----
__global__ __launch_bounds__(64) void vfe_scatter_atomic(
    const float* __restrict__ feat,
    const float* __restrict__ w1, const float* __restrict__ b1,
    const float* __restrict__ g1, const float* __restrict__ be1,
    const float* __restrict__ m1, const float* __restrict__ v1,
    const float* __restrict__ w2, const float* __restrict__ b2,
    const float* __restrict__ g2, const float* __restrict__ be2,
    const float* __restrict__ m2, const float* __restrict__ v2,
    const int* __restrict__ coord,
    float* __restrict__ out)
{
    const int k   = blockIdx.x;
    const int tid = threadIdx.x;
    __shared__ float sx[TPTS][FIN];
    __shared__ float smask[TPTS];
    __shared__ __align__(16) float sx2[TPTS][32];
    const float* fk = feat + (size_t)k * (TPTS * FIN);
    for (int i = tid; i < TPTS * FIN; i += 64) ((float*)sx)[i] = fk[i];
    __syncthreads();
    bool pred = false;
    if (tid < TPTS) {
        float mx = sx[tid][0];
        #pragma unroll
        for (int f = 1; f < FIN; ++f) mx = fmaxf(mx, sx[tid][f]);
        pred = (mx != 0.0f);
        smask[tid] = pred ? 1.0f : 0.0f;
    }
    unsigned long long bal = __ballot(pred);
    const int nvalid = __popcll(bal);
    __syncthreads();
    if (tid < 16) {
        const int u = tid;
        float w1c[FIN];
        #pragma unroll
        for (int f = 0; f < FIN; ++f) w1c[f] = w1[f * 16 + u];
        const float b = b1[u];
        const float scale = g1[u] * rsqrtf(v1[u] + EPSBN);
        const float shift = be1[u] - m1[u] * scale;
        float agg = -INFINITY;
        float pw[TPTS];
        #pragma unroll
        for (int t = 0; t < TPTS; ++t) {
            float d = b;
            #pragma unroll
            for (int f = 0; f < FIN; ++f) d = fmaf(sx[t][f], w1c[f], d);
            d = fmaxf(d, 0.0f);
            float p = fmaf(d, scale, shift);
            agg = fmaxf(agg, p);
            pw[t] = p;
        }
        #pragma unroll
        for (int t = 0; t < TPTS; ++t) {
            const float mk = smask[t];
            sx2[t][u] = pw[t] * mk;
            sx2[t][16 + u] = agg * mk;
        }
    }
    __syncthreads();
    {
        const int v = tid;
        float w2c[32];
        #pragma unroll
        for (int u = 0; u < 32; ++u) w2c[u] = w2[u * 64 + v];
        const float b = b2[v];
        const float scale = g2[v] * rsqrtf(v2[v] + EPSBN);
        const float shift = be2[v] - m2[v] * scale;
        float aggAll = -INFINITY, voxA = -INFINITY;
        #pragma unroll 5
        for (int t = 0; t < TPTS; ++t) {
            float d = b;
            const float4* xr = (const float4*)(&sx2[t][0]);
            #pragma unroll
            for (int q = 0; q < 8; ++q) {
                float4 xv = xr[q];
                d = fmaf(xv.x, w2c[4 * q + 0], d);
                d = fmaf(xv.y, w2c[4 * q + 1], d);
                d = fmaf(xv.z, w2c[4 * q + 2], d);
                d = fmaf(xv.w, w2c[4 * q + 3], d);
            }
            d = fmaxf(d, 0.0f);
            float p = fmaf(d, scale, shift);
            aggAll = fmaxf(aggAll, p);
            voxA = fmaxf(voxA, p * smask[t]);
        }
        float voxB;
        if (nvalid == 0) voxB = 0.0f;
        else if (nvalid < TPTS) voxB = fmaxf(aggAll, 0.0f);
        else voxB = aggAll;
        const int4 c = ((const int4*)coord)[k];
        const int loc = (((c.x * DD + c.y) * HH + c.z) * WW + c.w);
        float* o = out + (size_t)loc * CO;
        atomicAdd(o + v, voxA);
        atomicAdd(o + 64 + v, voxB);
    }
}

extern "C" void kernel_launch(void* const* d_in, const int* in_sizes, int n_in,
                              void* d_out, int out_size, void* d_ws, size_t ws_size,
                              hipStream_t stream) {
    const float* feat = (const float*)d_in[0];
    const float* w1   = (const float*)d_in[1];
    const float* b1   = (const float*)d_in[2];
    const float* g1   = (const float*)d_in[3];
    const float* be1  = (const float*)d_in[4];
    const float* m1   = (const float*)d_in[5];
    const float* v1   = (const float*)d_in[6];
    const float* w2   = (const float*)d_in[7];
    const float* b2   = (const float*)d_in[8];
    const float* g2   = (const float*)d_in[9];
    const float* be2  = (const float*)d_in[10];
    const float* m2   = (const float*)d_in[11];
    const float* v2   = (const float*)d_in[12];
    const int*   coord = (const int*)d_in[13];
    float* out = (float*)d_out;

    const size_t voxB = (size_t)KVOX * CO * sizeof(float);   // 6,144,000 B

    if (ws_size >= voxB) {
        float* vox = (float*)d_ws;
        fused_fill_compute<<<CB, 256, 0, stream>>>(feat, w1, b1, g1, be1, m1, v1,
                                                   w2, b2, g2, be2, m2, v2,
                                                   vox, out);
        scatter_add<<<SB, 256, 0, stream>>>(vox, coord, out);
    } else {
        hipMemsetAsync(d_out, 0, (size_t)out_size * sizeof(float), stream);
        vfe_scatter_atomic<<<KVOX, 64, 0, stream>>>(feat, w1, b1, g1, be1, m1, v1,
                                                    w2, b2, g2, be2, m2, v2, coord, out);
    }
}

// Round 9
// 749.731 us; speedup vs baseline: 1.0289x; 1.0289x over previous
//
#include <hip/hip_runtime.h>

#define KVOX 12000
#define TPTS 35
#define FIN  7
#define DD   10
#define HH   400
#define WW   352
#define CO   128
#define EPSBN 1e-3f
#define NCELL (DD * HH * WW)              // 1,408,000 cells
#define CB    3000                        // fused kernel blocks (4 waves = 4 voxels each)
#define TOTALF4 ((size_t)NCELL * 32)      // 45,056,000 float4s = 720.9 MB
#define SB    1500                        // scatter kernel blocks

static_assert(CB * 4 == KVOX, "grid covers voxels exactly");

// ---- fused: zero-fill `out` + compute voxelwise [KVOX,128] into ws ----
// R4 variant — best measured (753 us total). Phase-alternating fill/compute;
// simplest overlap structure. Write drain (720 MB @ ~6.3 TB/s = 115 us/CU-
// uniform) is the binding resource; fancier structures (strip-mine, role-
// split, barrier-free) all measured equal or worse (R5-R8).
__global__ __launch_bounds__(256) void fused_fill_compute(
    const float* __restrict__ feat,
    const float* __restrict__ w1, const float* __restrict__ b1,
    const float* __restrict__ g1, const float* __restrict__ be1,
    const float* __restrict__ m1, const float* __restrict__ v1,
    const float* __restrict__ w2, const float* __restrict__ b2,
    const float* __restrict__ g2, const float* __restrict__ be2,
    const float* __restrict__ m2, const float* __restrict__ v2,
    float* __restrict__ vox,          // [KVOX, 128]
    float* __restrict__ out)
{
    const int tid  = threadIdx.x;
    const int wv   = tid >> 6;        // wave in block: 0..3
    const int lane = tid & 63;
    const int k    = blockIdx.x * 4 + wv;

    __shared__ __align__(16) float sxp[4][TPTS][8];    // padded point features
    __shared__ __align__(16) float spwm[4][TPTS][16];  // masked stage-1 pointwise
    __shared__ __align__(16) float sagg[4][16];        // stage-1 aggregate (unmasked)

    const bool fillFirst = (blockIdx.x & 1);

    auto do_fill = [&]() {
        const float4 z = make_float4(0.f, 0.f, 0.f, 0.f);
        float4* o4 = (float4*)out;
        const size_t stride = (size_t)CB * 256;
        for (size_t i = (size_t)blockIdx.x * 256 + tid; i < TOTALF4; i += stride)
            o4[i] = z;
    };

    if (fillFirst) do_fill();

    // ---------------- compute: one wave per voxel ----------------
    const float* fk = feat + (size_t)k * (TPTS * FIN);

    // stage features into LDS, padded rows of 8 (row pad -> b128 reads later)
    for (int i = lane; i < TPTS * FIN; i += 64)
        sxp[wv][i / FIN][i % FIN] = fk[i];
    if (lane < TPTS) sxp[wv][lane][FIN] = 0.0f;

    // mask per point straight from global (L1/L2-hot)
    bool pred = false;
    if (lane < TPTS) {
        const float* row = fk + lane * FIN;
        float mx = row[0];
        #pragma unroll
        for (int f = 1; f < FIN; ++f) mx = fmaxf(mx, row[f]);
        pred = (mx != 0.0f);
    }
    const unsigned long long bal = __ballot(pred);   // bit t = mask[t] (wave-uniform)
    const int nvalid = __popcll(bal);
    __syncthreads();

    // stage 1: dense(7->16)+relu+BN on lanes u<16; agg over ALL t; masked store
    if (lane < 16) {
        const int u = lane;
        float w1c[8];
        #pragma unroll
        for (int f = 0; f < FIN; ++f) w1c[f] = w1[f * 16 + u];
        w1c[FIN] = 0.0f;
        const float b     = b1[u];
        const float scale = g1[u] * rsqrtf(v1[u] + EPSBN);
        const float shift = be1[u] - m1[u] * scale;

        float agg = -INFINITY;
        float pw[TPTS];
        #pragma unroll
        for (int t = 0; t < TPTS; ++t) {
            const float4 xa = *(const float4*)&sxp[wv][t][0];  // broadcast b128
            const float4 xb = *(const float4*)&sxp[wv][t][4];
            float d = b;
            d = fmaf(xa.x, w1c[0], d); d = fmaf(xa.y, w1c[1], d);
            d = fmaf(xa.z, w1c[2], d); d = fmaf(xa.w, w1c[3], d);
            d = fmaf(xb.x, w1c[4], d); d = fmaf(xb.y, w1c[5], d);
            d = fmaf(xb.z, w1c[6], d); d = fmaf(xb.w, w1c[7], d);
            d = fmaxf(d, 0.0f);
            const float p = fmaf(d, scale, shift);
            agg = fmaxf(agg, p);
            pw[t] = p;
        }
        sagg[wv][u] = agg;
        #pragma unroll
        for (int t = 0; t < TPTS; ++t) {
            const float mk = ((bal >> t) & 1ULL) ? 1.0f : 0.0f;
            spwm[wv][t][u] = pw[t] * mk;     // banks (t*16+u)%32: conflict-free
        }
    }
    __syncthreads();

    // stage 2: dense(32->64)+relu+BN, channel v per lane, agg-term factorized
    {
        const int v = lane;
        float w2c[32];
        #pragma unroll
        for (int u = 0; u < 32; ++u) w2c[u] = w2[u * 64 + v];
        const float b     = b2[v];
        const float scale = g2[v] * rsqrtf(v2[v] + EPSBN);
        const float shift = be2[v] - m2[v] * scale;

        // aggdot = sum_u agg[u] * w2c[16+u]  (t-independent)
        float aggdot = 0.0f;
        {
            const float4* ar = (const float4*)&sagg[wv][0];
            #pragma unroll
            for (int q = 0; q < 4; ++q) {
                const float4 a = ar[q];
                aggdot = fmaf(a.x, w2c[16 + 4 * q + 0], aggdot);
                aggdot = fmaf(a.y, w2c[16 + 4 * q + 1], aggdot);
                aggdot = fmaf(a.z, w2c[16 + 4 * q + 2], aggdot);
                aggdot = fmaf(a.w, w2c[16 + 4 * q + 3], aggdot);
            }
        }

        float aggAll = -INFINITY;
        float voxA   = -INFINITY;
        #pragma unroll 7
        for (int t = 0; t < TPTS; ++t) {
            const float mk = ((bal >> t) & 1ULL) ? 1.0f : 0.0f;
            const float4* xr = (const float4*)&spwm[wv][t][0];
            float d = fmaf(mk, aggdot, b);
            #pragma unroll
            for (int q = 0; q < 4; ++q) {
                const float4 xv = xr[q];          // broadcast b128
                d = fmaf(xv.x, w2c[4 * q + 0], d);
                d = fmaf(xv.y, w2c[4 * q + 1], d);
                d = fmaf(xv.z, w2c[4 * q + 2], d);
                d = fmaf(xv.w, w2c[4 * q + 3], d);
            }
            d = fmaxf(d, 0.0f);
            const float p = fmaf(d, scale, shift);
            aggAll = fmaxf(aggAll, p);
            voxA   = fmaxf(voxA, p * mk);
        }
        float voxB;
        if (nvalid == 0)          voxB = 0.0f;
        else if (nvalid < TPTS)   voxB = fmaxf(aggAll, 0.0f);
        else                      voxB = aggAll;

        float* vk = vox + (size_t)k * CO;
        vk[v]      = voxA;
        vk[64 + v] = voxB;
    }

    if (!fillFirst) do_fill();
}

// ---- tiny scatter: out[cell(k)*128 + ch] += vox[k*128 + ch] (dups accumulate) ----
__global__ __launch_bounds__(256) void scatter_add(
    const float* __restrict__ vox, const int* __restrict__ coord,
    float* __restrict__ out)
{
    const int stride = SB * 256;
    for (int i = blockIdx.x * 256 + threadIdx.x; i < KVOX * CO; i += stride) {
        const int k  = i >> 7;
        const int ch = i & (CO - 1);
        const int4 c = ((const int4*)coord)[k];   // 128 lanes share k -> L1 broadcast
        const int loc = (((c.x * DD + c.y) * HH + c.z) * WW + c.w);
        atomicAdd(out + (size_t)loc * CO + ch, vox[i]);
    }
}

// ---- fallback if ws is too small (R1 path) ----
__global__ __launch_bounds__(64) void vfe_scatter_atomic(
    const float* __restrict__ feat,
    const float* __restrict__ w1, const float* __restrict__ b1,
    const float* __restrict__ g1, const float* __restrict__ be1,
    const float* __restrict__ m1, const float* __restrict__ v1,
    const float* __restrict__ w2, const float* __restrict__ b2,
    const float* __restrict__ g2, const float* __restrict__ be2,
    const float* __restrict__ m2, const float* __restrict__ v2,
    const int* __restrict__ coord,
    float* __restrict__ out)
{
    const int k   = blockIdx.x;
    const int tid = threadIdx.x;
    __shared__ float sx[TPTS][FIN];
    __shared__ float smask[TPTS];
    __shared__ __align__(16) float sx2[TPTS][32];
    const float* fk = feat + (size_t)k * (TPTS * FIN);
    for (int i = tid; i < TPTS * FIN; i += 64) ((float*)sx)[i] = fk[i];
    __syncthreads();
    bool pred = false;
    if (tid < TPTS) {
        float mx = sx[tid][0];
        #pragma unroll
        for (int f = 1; f < FIN; ++f) mx = fmaxf(mx, sx[tid][f]);
        pred = (mx != 0.0f);
        smask[tid] = pred ? 1.0f : 0.0f;
    }
    unsigned long long bal = __ballot(pred);
    const int nvalid = __popcll(bal);
    __syncthreads();
    if (tid < 16) {
        const int u = tid;
        float w1c[FIN];
        #pragma unroll
        for (int f = 0; f < FIN; ++f) w1c[f] = w1[f * 16 + u];
        const float b = b1[u];
        const float scale = g1[u] * rsqrtf(v1[u] + EPSBN);
        const float shift = be1[u] - m1[u] * scale;
        float agg = -INFINITY;
        float pw[TPTS];
        #pragma unroll
        for (int t = 0; t < TPTS; ++t) {
            float d = b;
            #pragma unroll
            for (int f = 0; f < FIN; ++f) d = fmaf(sx[t][f], w1c[f], d);
            d = fmaxf(d, 0.0f);
            float p = fmaf(d, scale, shift);
            agg = fmaxf(agg, p);
            pw[t] = p;
        }
        #pragma unroll
        for (int t = 0; t < TPTS; ++t) {
            const float mk = smask[t];
            sx2[t][u] = pw[t] * mk;
            sx2[t][16 + u] = agg * mk;
        }
    }
    __syncthreads();
    {
        const int v = tid;
        float w2c[32];
        #pragma unroll
        for (int u = 0; u < 32; ++u) w2c[u] = w2[u * 64 + v];
        const float b = b2[v];
        const float scale = g2[v] * rsqrtf(v2[v] + EPSBN);
        const float shift = be2[v] - m2[v] * scale;
        float aggAll = -INFINITY, voxA = -INFINITY;
        #pragma unroll 5
        for (int t = 0; t < TPTS; ++t) {
            float d = b;
            const float4* xr = (const float4*)(&sx2[t][0]);
            #pragma unroll
            for (int q = 0; q < 8; ++q) {
                float4 xv = xr[q];
                d = fmaf(xv.x, w2c[4 * q + 0], d);
                d = fmaf(xv.y, w2c[4 * q + 1], d);
                d = fmaf(xv.z, w2c[4 * q + 2], d);
                d = fmaf(xv.w, w2c[4 * q + 3], d);
            }
            d = fmaxf(d, 0.0f);
            float p = fmaf(d, scale, shift);
            aggAll = fmaxf(aggAll, p);
            voxA = fmaxf(voxA, p * smask[t]);
        }
        float voxB;
        if (nvalid == 0) voxB = 0.0f;
        else if (nvalid < TPTS) voxB = fmaxf(aggAll, 0.0f);
        else voxB = aggAll;
        const int4 c = ((const int4*)coord)[k];
        const int loc = (((c.x * DD + c.y) * HH + c.z) * WW + c.w);
        float* o = out + (size_t)loc * CO;
        atomicAdd(o + v, voxA);
        atomicAdd(o + 64 + v, voxB);
    }
}

extern "C" void kernel_launch(void* const* d_in, const int* in_sizes, int n_in,
                              void* d_out, int out_size, void* d_ws, size_t ws_size,
                              hipStream_t stream) {
    const float* feat = (const float*)d_in[0];
    const float* w1   = (const float*)d_in[1];
    const float* b1   = (const float*)d_in[2];
    const float* g1   = (const float*)d_in[3];
    const float* be1  = (const float*)d_in[4];
    const float* m1   = (const float*)d_in[5];
    const float* v1   = (const float*)d_in[6];
    const float* w2   = (const float*)d_in[7];
    const float* b2   = (const float*)d_in[8];
    const float* g2   = (const float*)d_in[9];
    const float* be2  = (const float*)d_in[10];
    const float* m2   = (const float*)d_in[11];
    const float* v2   = (const float*)d_in[12];
    const int*   coord = (const int*)d_in[13];
    float* out = (float*)d_out;

    const size_t voxB = (size_t)KVOX * CO * sizeof(float);   // 6,144,000 B

    if (ws_size >= voxB) {
        float* vox = (float*)d_ws;
        fused_fill_compute<<<CB, 256, 0, stream>>>(feat, w1, b1, g1, be1, m1, v1,
                                                   w2, b2, g2, be2, m2, v2,
                                                   vox, out);
        scatter_add<<<SB, 256, 0, stream>>>(vox, coord, out);
    } else {
        hipMemsetAsync(d_out, 0, (size_t)out_size * sizeof(float), stream);
        vfe_scatter_atomic<<<KVOX, 64, 0, stream>>>(feat, w1, b1, g1, be1, m1, v1,
                                                    w2, b2, g2, be2, m2, v2, coord, out);
    }
}